// Round 10
// baseline (157.137 us; speedup 1.0000x reference)
//
#include <hip/hip_runtime.h>
#include <hip/hip_bf16.h>

// ---------------------------------------------------------------------------
// ASL RNN.  Structure (verified):
//  * recurrence never reads i2h -> only frame T-1 (512 samples) runs conv/fc.
//  * h_32 via 5 matrix squarings + vector recurrence.
// Round 10 = R9 (149.1us) with ONE change: the squaring chain uses bf16 MFMA
// with fp32-emulation (hi/lo split, 3 products), one launch per level
// (no split-K -> no reduce launches).  10 launches -> 6 for the chain.
// Dead ends (measured): role-merged mega-kernels (R4/R6), sum-on-load (R5),
// cooperative grid.sync ~35us/sync (R7), atomic split-K accumulate (R8).
// ---------------------------------------------------------------------------

typedef __attribute__((ext_vector_type(8))) unsigned short us8;
typedef __attribute__((ext_vector_type(8))) __bf16 bf8v;
typedef __attribute__((ext_vector_type(4))) float f4v;

static __device__ __forceinline__ unsigned short f2bf(float x) {
    __hip_bfloat16 h = __float2bfloat16(x);
    return *reinterpret_cast<unsigned short*>(&h);
}
static __device__ __forceinline__ float bf2f(unsigned short u) {
    __hip_bfloat16 h = *reinterpret_cast<__hip_bfloat16*>(&u);
    return __bfloat162float(h);
}
static __device__ __forceinline__ void splitf(float f, unsigned short& h,
                                              unsigned short& l) {
    h = f2bf(f);
    l = f2bf(f - bf2f(h));
}

static __device__ __forceinline__ void gload16(const void* g, void* s) {
    typedef __attribute__((address_space(1))) const void gv_t;
    typedef __attribute__((address_space(3))) void sv_t;
    __builtin_amdgcn_global_load_lds((gv_t*)g, (sv_t*)s, 16, 0, 0);
}

static __device__ __forceinline__ float4 ldg4_guard(
    const float* __restrict__ p, int r, int R, int c, int C, int ld)
{
    float4 v = make_float4(0.f, 0.f, 0.f, 0.f);
    if (r < R) {
        if (c + 3 < C) {
            v = *(const float4*)(p + (size_t)r * ld + c);
        } else {
            float tmp[4] = {0.f, 0.f, 0.f, 0.f};
            for (int u = 0; u < 4; ++u)
                if (c + u < C) tmp[u] = p[(size_t)r * ld + c + u];
            v = make_float4(tmp[0], tmp[1], tmp[2], tmp[3]);
        }
    }
    return v;
}

// ---------------------------------------------------------------------------
// bf16 MFMA GEMM partials (R9 verbatim): Cp[z] = feat[:,chunk_z] @ W[:,chunk_z]^T
// ---------------------------------------------------------------------------
#define KSTR 9536   // padded K (bf16 elems), 149 stages of 64

__global__ __launch_bounds__(256, 2) void mfma_bt(
    const unsigned short* __restrict__ A, const unsigned short* __restrict__ B,
    float* __restrict__ Cp, int nper, int ntot)
{
    __shared__ alignas(16) unsigned short Al[2][4096];
    __shared__ alignas(16) unsigned short Bl[2][4096];
    const int lid = blockIdx.x;
    const int z = lid & 7;
    const int bm = ((lid >> 3) & 7) * 64, bn = (lid >> 6) * 64;
    int s0 = z * nper;
    int s1 = s0 + nper; if (s1 > ntot) s1 = ntot;
    const int ns = s1 - s0;
    const int t = threadIdx.x, w = t >> 6, l = t & 63;
    const int srow = l >> 3;
    const int sslot = (l & 7) ^ srow;
    const int wm = (w >> 1) * 32, wn = (w & 1) * 32;
    const int fr = l & 15, jj = l >> 4;
    f4v acc[2][2] = {};

    const unsigned short* Ab = A + (size_t)(bm + 16 * w + srow) * KSTR + sslot * 8;
    const unsigned short* Bb = B + (size_t)(bn + 16 * w + srow) * KSTR + sslot * 8;

#define STAGE(buf, st)                                                          \
    {                                                                           \
        size_t k0 = (size_t)(s0 + (st)) * 64;                                   \
        _Pragma("unroll")                                                       \
        for (int q = 0; q < 2; ++q) {                                           \
            gload16(Ab + (size_t)(8 * q) * KSTR + k0,                           \
                    &Al[buf][(16 * w + 8 * q) * 64]);                           \
            gload16(Bb + (size_t)(8 * q) * KSTR + k0,                           \
                    &Bl[buf][(16 * w + 8 * q) * 64]);                           \
        }                                                                       \
    }

#define COMPUTE(buf)                                                            \
    {                                                                           \
        _Pragma("unroll")                                                       \
        for (int kk = 0; kk < 2; ++kk) {                                        \
            bf8v af[2], bf[2];                                                  \
            _Pragma("unroll")                                                   \
            for (int f = 0; f < 2; ++f) {                                       \
                int rA = wm + f * 16 + fr;                                      \
                int pA = (jj + 4 * kk) ^ (rA & 7);                              \
                af[f] = __builtin_bit_cast(bf8v,                                \
                        *(const us8*)&Al[buf][rA * 64 + pA * 8]);               \
                int rB = wn + f * 16 + fr;                                      \
                int pB = (jj + 4 * kk) ^ (rB & 7);                              \
                bf[f] = __builtin_bit_cast(bf8v,                                \
                        *(const us8*)&Bl[buf][rB * 64 + pB * 8]);               \
            }                                                                   \
            _Pragma("unroll")                                                   \
            for (int fi = 0; fi < 2; ++fi)                                      \
                _Pragma("unroll")                                               \
                for (int fj = 0; fj < 2; ++fj)                                  \
                    acc[fi][fj] = __builtin_amdgcn_mfma_f32_16x16x32_bf16(      \
                        af[fi], bf[fj], acc[fi][fj], 0, 0, 0);                  \
        }                                                                       \
    }

    STAGE(0, 0);
    __syncthreads();
    int cur = 0;
    for (int st = 0; st < ns; ++st) {
        if (st + 1 < ns) STAGE(cur ^ 1, st + 1);
        COMPUTE(cur);
        __syncthreads();
        cur ^= 1;
    }

    float* Cz = Cp + (size_t)z * 262144;
#pragma unroll
    for (int fi = 0; fi < 2; ++fi)
#pragma unroll
        for (int fj = 0; fj < 2; ++fj)
#pragma unroll
            for (int r = 0; r < 4; ++r) {
                int m = bm + wm + fi * 16 + jj * 4 + r;
                int n = bn + wn + fj * 16 + fr;
                Cz[(size_t)m * 512 + n] = acc[fi][fj][r];
            }
#undef STAGE
#undef COMPUTE
}

// ---------------------------------------------------------------------------
// prep_pw: hw (500x500 f32) -> hi/lo bf16 in row-major AND col-major
// padded [512][512] forms (pads zero).  64 blocks, LDS-tiled transpose.
// ---------------------------------------------------------------------------
__global__ __launch_bounds__(256) void prep_pw(
    const float* __restrict__ P,
    unsigned short* __restrict__ hiR, unsigned short* __restrict__ loR,
    unsigned short* __restrict__ hiC, unsigned short* __restrict__ loC)
{
    __shared__ unsigned short shH[64][65];
    __shared__ unsigned short shL[64][65];
    const int bm = (blockIdx.x & 7) * 64, bn = (blockIdx.x >> 3) * 64;
    const int t = threadIdx.x;
    for (int idx = t; idx < 4096; idx += 256) {
        int m = idx >> 6, n = idx & 63;
        int gm = bm + m, gn = bn + n;
        float f = (gm < 500 && gn < 500) ? P[(size_t)gm * 500 + gn] : 0.f;
        unsigned short h, l;
        splitf(f, h, l);
        hiR[(size_t)gm * 512 + gn] = h;
        loR[(size_t)gm * 512 + gn] = l;
        shH[m][n] = h; shL[m][n] = l;
    }
    __syncthreads();
    for (int idx = t; idx < 4096; idx += 256) {
        int nn = idx >> 6, mm = idx & 63;
        hiC[(size_t)(bn + nn) * 512 + bm + mm] = shH[mm][nn];
        loC[(size_t)(bn + nn) * 512 + bm + mm] = shL[mm][nn];
    }
}

// ---------------------------------------------------------------------------
// sq_mfma: one squaring level in one launch.
// gemm blocks (lid<64): C = P@P via bt-form MFMA with A = P rows (hiR/loR),
// B = P^T rows (hiC/loC); 3 products hi*hi + hi*lo + lo*hi, fp32 acc.
// Epilogue: fp32 dst (stride 500) + next level's hi/lo row+col (if dhiR).
// vec blocks (lid>=64): u_out = u_in + u_in @ vsrc^T  (vsrc = this level's P).
// ---------------------------------------------------------------------------
__global__ __launch_bounds__(256, 2) void sq_mfma(
    const unsigned short* __restrict__ hiR, const unsigned short* __restrict__ loR,
    const unsigned short* __restrict__ hiC, const unsigned short* __restrict__ loC,
    float* __restrict__ dstF,
    unsigned short* __restrict__ dhiR, unsigned short* __restrict__ dloR,
    unsigned short* __restrict__ dhiC, unsigned short* __restrict__ dloC,
    const float* __restrict__ vsrc, const float* __restrict__ u_in,
    float* __restrict__ u_out)
{
    __shared__ alignas(16) unsigned short AhiL[2][4096];
    __shared__ alignas(16) unsigned short AloL[2][4096];
    __shared__ alignas(16) unsigned short BhiL[2][4096];
    __shared__ alignas(16) unsigned short BloL[2][4096];
    const int lid = blockIdx.x, t = threadIdx.x;
    if (lid >= 64) {
        const int j = lid - 64;
        float* red = (float*)AhiL;
        float s = 0.f;
        for (int a = t; a < 500; a += 256)
            s += u_in[a] * vsrc[(size_t)j * 500 + a];
        for (int off = 32; off; off >>= 1) s += __shfl_down(s, off);
        if ((t & 63) == 0) red[t >> 6] = s;
        __syncthreads();
        if (t == 0) u_out[j] = red[0] + red[1] + red[2] + red[3] + u_in[j];
        return;
    }
    const int bm = (lid & 7) * 64, bn = (lid >> 3) * 64;
    const int w = t >> 6, l = t & 63;
    const int srow = l >> 3;
    const int sslot = (l & 7) ^ srow;
    const int wm = (w >> 1) * 32, wn = (w & 1) * 32;
    const int fr = l & 15, jj = l >> 4;
    f4v acc[2][2] = {};

    const size_t offA = (size_t)(bm + 16 * w + srow) * 512 + sslot * 8;
    const size_t offB = (size_t)(bn + 16 * w + srow) * 512 + sslot * 8;

#define SQSTAGE(buf, st)                                                        \
    {                                                                           \
        size_t k0 = (size_t)(st) * 64;                                          \
        _Pragma("unroll")                                                       \
        for (int q = 0; q < 2; ++q) {                                           \
            size_t sa = offA + (size_t)(8 * q) * 512 + k0;                      \
            size_t sb = offB + (size_t)(8 * q) * 512 + k0;                      \
            gload16(hiR + sa, &AhiL[buf][(16 * w + 8 * q) * 64]);               \
            gload16(loR + sa, &AloL[buf][(16 * w + 8 * q) * 64]);               \
            gload16(hiC + sb, &BhiL[buf][(16 * w + 8 * q) * 64]);               \
            gload16(loC + sb, &BloL[buf][(16 * w + 8 * q) * 64]);               \
        }                                                                       \
    }
#define SQCOMPUTE(buf)                                                          \
    {                                                                           \
        _Pragma("unroll")                                                       \
        for (int kk = 0; kk < 2; ++kk) {                                        \
            bf8v ah[2], al[2], bh[2], bl[2];                                    \
            _Pragma("unroll")                                                   \
            for (int f = 0; f < 2; ++f) {                                       \
                int rA = wm + f * 16 + fr;                                      \
                int pA = (jj + 4 * kk) ^ (rA & 7);                              \
                ah[f] = __builtin_bit_cast(bf8v,                                \
                        *(const us8*)&AhiL[buf][rA * 64 + pA * 8]);             \
                al[f] = __builtin_bit_cast(bf8v,                                \
                        *(const us8*)&AloL[buf][rA * 64 + pA * 8]);             \
                int rB = wn + f * 16 + fr;                                      \
                int pB = (jj + 4 * kk) ^ (rB & 7);                              \
                bh[f] = __builtin_bit_cast(bf8v,                                \
                        *(const us8*)&BhiL[buf][rB * 64 + pB * 8]);             \
                bl[f] = __builtin_bit_cast(bf8v,                                \
                        *(const us8*)&BloL[buf][rB * 64 + pB * 8]);             \
            }                                                                   \
            _Pragma("unroll")                                                   \
            for (int fi = 0; fi < 2; ++fi)                                      \
                _Pragma("unroll")                                               \
                for (int fj = 0; fj < 2; ++fj) {                                \
                    acc[fi][fj] = __builtin_amdgcn_mfma_f32_16x16x32_bf16(      \
                        ah[fi], bh[fj], acc[fi][fj], 0, 0, 0);                  \
                    acc[fi][fj] = __builtin_amdgcn_mfma_f32_16x16x32_bf16(      \
                        ah[fi], bl[fj], acc[fi][fj], 0, 0, 0);                  \
                    acc[fi][fj] = __builtin_amdgcn_mfma_f32_16x16x32_bf16(      \
                        al[fi], bh[fj], acc[fi][fj], 0, 0, 0);                  \
                }                                                               \
        }                                                                       \
    }

    SQSTAGE(0, 0);
    __syncthreads();
    int cur = 0;
    for (int st = 0; st < 8; ++st) {
        if (st + 1 < 8) SQSTAGE(cur ^ 1, st + 1);
        SQCOMPUTE(cur);
        __syncthreads();
        cur ^= 1;
    }

#pragma unroll
    for (int fi = 0; fi < 2; ++fi)
#pragma unroll
        for (int fj = 0; fj < 2; ++fj)
#pragma unroll
            for (int r = 0; r < 4; ++r) {
                int m = bm + wm + fi * 16 + jj * 4 + r;
                int n = bn + wn + fj * 16 + fr;
                float v = acc[fi][fj][r];
                if (m < 500 && n < 500) dstF[(size_t)m * 500 + n] = v;
                if (dhiR) {
                    unsigned short h, lo2;
                    splitf(v, h, lo2);
                    dhiR[(size_t)m * 512 + n] = h;
                    dloR[(size_t)m * 512 + n] = lo2;
                    dhiC[(size_t)n * 512 + m] = h;
                    dloC[(size_t)n * 512 + m] = lo2;
                }
            }
#undef SQSTAGE
#undef SQCOMPUTE
}

// ---------------------------------------------------------------------------
// fp32 64x64-tile GEMM variants (R9 verbatim)
// ---------------------------------------------------------------------------
__global__ __launch_bounds__(256) void fc_gemm(
    const float* __restrict__ hpL, const float* __restrict__ hpR,
    const float* __restrict__ lfw, const float* __restrict__ rfw,
    const float* __restrict__ lfb, const float* __restrict__ rfb,
    float* __restrict__ both)
{
    __shared__ alignas(16) float As[16][68];
    __shared__ alignas(16) float Bs[16][68];
    const int hand = blockIdx.z;
    const float* A = hand ? hpR : hpL;
    const float* B = hand ? rfw : lfw;
    const float* bias = hand ? rfb : lfb;
    const int t = threadIdx.x;
    const int bm = blockIdx.x * 64, bn = blockIdx.y * 64;
    const int lr = t >> 2, kq = (t & 3) * 4;
    const int ty = t >> 4, tx = t & 15;
    float acc[4][4] = {};
    float4 a0 = *(const float4*)(A + (size_t)(bm + lr) * 304 + kq);
    float4 b0 = (bn + lr < 300)
        ? *(const float4*)(B + (size_t)(bn + lr) * 304 + kq)
        : make_float4(0.f, 0.f, 0.f, 0.f);
    for (int ks = 0; ks < 19; ++ks) {
        __syncthreads();
        As[kq + 0][lr] = a0.x; As[kq + 1][lr] = a0.y;
        As[kq + 2][lr] = a0.z; As[kq + 3][lr] = a0.w;
        Bs[kq + 0][lr] = b0.x; Bs[kq + 1][lr] = b0.y;
        Bs[kq + 2][lr] = b0.z; Bs[kq + 3][lr] = b0.w;
        __syncthreads();
        if (ks < 18) {
            int kb = (ks + 1) * 16 + kq;
            a0 = *(const float4*)(A + (size_t)(bm + lr) * 304 + kb);
            b0 = (bn + lr < 300)
                ? *(const float4*)(B + (size_t)(bn + lr) * 304 + kb)
                : make_float4(0.f, 0.f, 0.f, 0.f);
        }
#pragma unroll
        for (int k = 0; k < 16; ++k) {
            float4 av = *(const float4*)&As[k][ty * 4];
            float4 bv = *(const float4*)&Bs[k][tx * 4];
            float aa[4] = {av.x, av.y, av.z, av.w};
            float bb[4] = {bv.x, bv.y, bv.z, bv.w};
#pragma unroll
            for (int i = 0; i < 4; ++i)
#pragma unroll
                for (int j = 0; j < 4; ++j)
                    acc[i][j] = fmaf(aa[i], bb[j], acc[i][j]);
        }
    }
#pragma unroll
    for (int i = 0; i < 4; ++i) {
        int m = bm + ty * 4 + i;
#pragma unroll
        for (int j = 0; j < 4; ++j) {
            int n = bn + tx * 4 + j;
            if (n < 300)
                both[(size_t)m * 600 + hand * 300 + n] =
                    fmaxf(acc[i][j] + bias[n], 0.f);
        }
    }
}

// h partial: Hsum[z] = hidden[:, chunk] * P32[:, chunk]^T  (R9 verbatim)
__global__ __launch_bounds__(256) void h_gemm(
    const float* __restrict__ A, const float* __restrict__ B,
    float* __restrict__ Hsum)
{
    __shared__ alignas(16) float As[16][68];
    __shared__ alignas(16) float Bs[16][68];
    const int t = threadIdx.x;
    const int bm = blockIdx.x * 64, bn = blockIdx.y * 64, z = blockIdx.z;
    const int k0 = z * 128;
    const int kend = (k0 + 128 < 500) ? k0 + 128 : 500;
    const int lr = t >> 2, kq = (t & 3) * 4;
    const int ty = t >> 4, tx = t & 15;
    float acc[4][4] = {};
    float4 a0 = ldg4_guard(A, bm + lr, 512, k0 + kq, kend, 500);
    float4 b0 = ldg4_guard(B, bn + lr, 500, k0 + kq, kend, 500);
    for (int ks = 0; ks < 8; ++ks) {
        __syncthreads();
        As[kq + 0][lr] = a0.x; As[kq + 1][lr] = a0.y;
        As[kq + 2][lr] = a0.z; As[kq + 3][lr] = a0.w;
        Bs[kq + 0][lr] = b0.x; Bs[kq + 1][lr] = b0.y;
        Bs[kq + 2][lr] = b0.z; Bs[kq + 3][lr] = b0.w;
        __syncthreads();
        if (ks < 7) {
            a0 = ldg4_guard(A, bm + lr, 512, k0 + (ks + 1) * 16 + kq, kend, 500);
            b0 = ldg4_guard(B, bn + lr, 500, k0 + (ks + 1) * 16 + kq, kend, 500);
        }
#pragma unroll
        for (int k = 0; k < 16; ++k) {
            float4 av = *(const float4*)&As[k][ty * 4];
            float4 bv = *(const float4*)&Bs[k][tx * 4];
            float aa[4] = {av.x, av.y, av.z, av.w};
            float bb[4] = {bv.x, bv.y, bv.z, bv.w};
#pragma unroll
            for (int i = 0; i < 4; ++i)
#pragma unroll
                for (int j = 0; j < 4; ++j)
                    acc[i][j] = fmaf(aa[i], bb[j], acc[i][j]);
        }
    }
    float* Cz = Hsum + (size_t)z * 256000;
#pragma unroll
    for (int i = 0; i < 4; ++i) {
        int m = bm + ty * 4 + i;
#pragma unroll
        for (int j = 0; j < 4; ++j) {
            int n = bn + tx * 4 + j;
            if (n < 500) Cz[(size_t)m * 500 + n] = acc[i][j];
        }
    }
}

// ---------------------------------------------------------------------------
// small fused kernels (R9 verbatim)
// ---------------------------------------------------------------------------
__global__ __launch_bounds__(128) void hand_conv(
    const float* __restrict__ hand,
    const float* __restrict__ lcw, const float* __restrict__ lcb,
    const float* __restrict__ rcw, const float* __restrict__ rcb,
    float* __restrict__ hpL, float* __restrict__ hpR)
{
    const int b = blockIdx.x;
    __shared__ float x[84];
    __shared__ float cw[2][64];
    __shared__ float cb[2][16];
    const int t = threadIdx.x;
    if (t < 84) x[t] = hand[(size_t)b * 84 + t];
    if (t < 64) { cw[0][t] = lcw[t]; cw[1][t] = rcw[t]; }
    if (t < 16) { cb[0][t] = lcb[t]; cb[1][t] = rcb[t]; }
    __syncthreads();
    for (int idx = t; idx < 608; idx += 128) {
        int hi = idx / 304, rem = idx % 304;
        int o = rem / 19, p = rem % 19;
        int off = hi * 42;
        const float* w = cw[hi];
        float w00 = w[o * 4], w01 = w[o * 4 + 1], w10 = w[o * 4 + 2], w11 = w[o * 4 + 3];
        float bs = cb[hi][o];
        float c0 = w00 * x[off + 2 * p] + w01 * x[off + 2 * p + 2] +
                   w10 * x[off + 2 * p + 1] + w11 * x[off + 2 * p + 3] + bs;
        float c1 = w00 * x[off + 2 * p + 2] + w01 * x[off + 2 * p + 4] +
                   w10 * x[off + 2 * p + 3] + w11 * x[off + 2 * p + 5] + bs;
        float v = fmaxf(fmaxf(c0, c1), 0.f);
        (hi ? hpR : hpL)[(size_t)b * 304 + rem] = v;
    }
}

__global__ __launch_bounds__(256) void conv2_feat(
    const float* __restrict__ both, const float* __restrict__ w2g,
    const float* __restrict__ b2g, unsigned short* __restrict__ feat)
{
    const int b = blockIdx.x, t = threadIdx.x;
    __shared__ float s[600];
    __shared__ float w2[128];
    __shared__ float b2[32];
    for (int i = t; i < 600; i += 256) s[i] = both[(size_t)b * 600 + i];
    if (t < 128) w2[t] = w2g[t];
    if (t < 32) b2[t] = b2g[t];
    __syncthreads();
    for (int idx = t; idx < 9536; idx += 256) {
        unsigned short ov = 0;
        if (idx < 9504) {
            int o = idx / 297, p = idx - o * 297;
            float w0 = w2[o * 4], w1 = w2[o * 4 + 1];
            float w2v = w2[o * 4 + 2], w3 = w2[o * 4 + 3], bb = b2[o];
            float m = -1e30f;
#pragma unroll
            for (int q = 0; q < 3; ++q) {
                float c = w0 * s[p + q] + w1 * s[p + q + 1] +
                          w2v * s[300 + p + q] + w3 * s[301 + p + q] + bb;
                m = fmaxf(m, c);
            }
            ov = f2bf(fmaxf(m, 0.f));
        }
        feat[(size_t)b * 9536 + idx] = ov;
    }
}

__global__ __launch_bounds__(256) void cvt_w(
    const float* __restrict__ W, unsigned short* __restrict__ Wb)
{
    int idx = blockIdx.x * 256 + threadIdx.x;
    int row = idx / 1192;
    int k8 = (idx - row * 1192) * 8;
    if (row >= 512) return;
    us8 o = (us8)0;
    if (row < 500 && k8 < 9504) {
        const float* p = W + (size_t)row * 9504 + k8;
        float4 v0 = *(const float4*)p;
        float4 v1 = *(const float4*)(p + 4);
        o[0] = f2bf(v0.x); o[1] = f2bf(v0.y); o[2] = f2bf(v0.z); o[3] = f2bf(v0.w);
        o[4] = f2bf(v1.x); o[5] = f2bf(v1.y); o[6] = f2bf(v1.z); o[7] = f2bf(v1.w);
    }
    *(us8*)(Wb + (size_t)row * 9536 + k8) = o;
}

__global__ __launch_bounds__(256) void out_final(
    const float* __restrict__ Cp, const float* __restrict__ l2b,
    const float* __restrict__ Hsum, const float* __restrict__ u32,
    const float* __restrict__ ow, const float* __restrict__ ob,
    float* __restrict__ out, float* __restrict__ hout)
{
    const int b = blockIdx.x, t = threadIdx.x;
    __shared__ float sj[512];
    __shared__ float red[10][4];
    for (int j = t; j < 500; j += 256) {
        float ih = l2b[j];
#pragma unroll
        for (int zz = 0; zz < 8; ++zz)
            ih += Cp[(size_t)zz * 262144 + (size_t)b * 512 + j];
        float h = u32[j];
#pragma unroll
        for (int zz = 0; zz < 4; ++zz)
            h += Hsum[(size_t)zz * 256000 + (size_t)b * 500 + j];
        hout[(size_t)b * 500 + j] = h;
        sj[j] = ih + h;
    }
    __syncthreads();
    const int w = t >> 6;
    for (int o = 0; o < 10; ++o) {
        float acc = 0.f;
        if (t < 500) acc += sj[t] * ow[o * 500 + t];
        if (t + 256 < 500) acc += sj[t + 256] * ow[o * 500 + t + 256];
        for (int off = 32; off; off >>= 1) acc += __shfl_down(acc, off);
        if ((t & 63) == 0) red[o][w] = acc;
    }
    __syncthreads();
    if (t < 10)
        out[(size_t)b * 10 + t] =
            fmaxf(red[t][0] + red[t][1] + red[t][2] + red[t][3] + ob[t], 0.f);
}

extern "C" void kernel_launch(void* const* d_in, const int* in_sizes, int n_in,
                              void* d_out, int out_size, void* d_ws, size_t ws_size,
                              hipStream_t stream) {
    const float* hand   = (const float*)d_in[0];
    const float* hidden = (const float*)d_in[1];
    const float* lcw = (const float*)d_in[2];
    const float* lcb = (const float*)d_in[3];
    const float* lfw = (const float*)d_in[4];
    const float* lfb = (const float*)d_in[5];
    const float* rcw = (const float*)d_in[6];
    const float* rcb = (const float*)d_in[7];
    const float* rfw = (const float*)d_in[8];
    const float* rfb = (const float*)d_in[9];
    const float* w2  = (const float*)d_in[10];
    const float* b2  = (const float*)d_in[11];
    const float* l2w = (const float*)d_in[12];
    const float* l2b = (const float*)d_in[13];
    const float* hw  = (const float*)d_in[14];
    const float* hb  = (const float*)d_in[15];
    const float* ow  = (const float*)d_in[16];
    const float* ob  = (const float*)d_in[17];

    char* wsb = (char*)d_ws;
    // [0, 8MB): Cp (mfma partials).  Early overlay: hpL/hpR/both (dead before
    // mfma_bt writes Cp).
    float* Cp   = (float*)wsb;
    float* hpL  = (float*)wsb;
    float* hpR  = (float*)(wsb + 622592);
    float* both = (float*)(wsb + 1245184);
    // [8MB, +19.53MB): featb + wbf, dead after mfma_bt; overlaid by the sq
    // chain buffers (all sq launches come after mfma_bt in stream order).
    char* base1 = wsb + 8388608;
    unsigned short* featb = (unsigned short*)base1;             // 9,764,864 B
    unsigned short* wbf   = (unsigned short*)(base1 + 9764864); // 9,764,864 B
    float* Pa = (float*)base1;                        // 1,000,000 B
    float* Pb = (float*)(base1 + 1000000);            // 1,000,000 B
    float* ua = (float*)(base1 + 2000000);            // 2,048 B
    float* ub = (float*)(base1 + 2002048);            // 2,048 B
    unsigned short* hiRA = (unsigned short*)(base1 + 2004096);  // 524,288 each
    unsigned short* loRA = hiRA + 262144;
    unsigned short* hiCA = loRA + 262144;
    unsigned short* loCA = hiCA + 262144;
    unsigned short* hiRB = loCA + 262144;
    unsigned short* loRB = hiRB + 262144;
    unsigned short* hiCB = loRB + 262144;
    unsigned short* loCB = hiCB + 262144;             // ends base1+6,198,400
    float* Hsum = (float*)(base1 + 9764864);          // 4 x 1,024,000 B

    float* out  = (float*)d_out;
    float* hout = out + 5120;

    // feature pipeline (frame 31 only)
    cvt_w<<<2384, 256, 0, stream>>>(l2w, wbf);
    hand_conv<<<512, 128, 0, stream>>>(hand + (size_t)31 * 512 * 84,
                                       lcw, lcb, rcw, rcb, hpL, hpR);
    fc_gemm<<<dim3(8, 5, 2), 256, 0, stream>>>(hpL, hpR, lfw, rfw, lfb, rfb, both);
    conv2_feat<<<512, 256, 0, stream>>>(both, w2, b2, featb);
    mfma_bt<<<512, 256, 0, stream>>>(featb, wbf, Cp, 19, 149);

    // recurrence: hi/lo prep + 5 MFMA squaring levels (one launch each)
    prep_pw<<<64, 256, 0, stream>>>(hw, hiRA, loRA, hiCA, loCA);
    sq_mfma<<<564, 256, 0, stream>>>(hiRA, loRA, hiCA, loCA, Pa,
                                     hiRB, loRB, hiCB, loCB, hw, hb, ua);
    sq_mfma<<<564, 256, 0, stream>>>(hiRB, loRB, hiCB, loCB, Pb,
                                     hiRA, loRA, hiCA, loCA, Pa, ua, ub);
    sq_mfma<<<564, 256, 0, stream>>>(hiRA, loRA, hiCA, loCA, Pa,
                                     hiRB, loRB, hiCB, loCB, Pb, ub, ua);
    sq_mfma<<<564, 256, 0, stream>>>(hiRB, loRB, hiCB, loCB, Pb,
                                     hiRA, loRA, hiCA, loCA, Pa, ua, ub);
    sq_mfma<<<564, 256, 0, stream>>>(hiRA, loRA, hiCA, loCA, Pa,
                                     nullptr, nullptr, nullptr, nullptr,
                                     Pb, ub, ua);

    // h partials (hidden @ P32^T), then final reduce + output GEMV
    h_gemm<<<dim3(8, 8, 4), 256, 0, stream>>>(hidden, Pa, Hsum);
    out_final<<<512, 256, 0, stream>>>(Cp, l2b, Hsum, ua, ow, ob, out, hout);
}